// Round 11
// baseline (839.206 us; speedup 1.0000x reference)
//
#include <hip/hip_runtime.h>

#define S_TOK 32768
#define DIN   2048
#define NH    8
#define NG    4
#define DH    128
#define NSINK 16
#define BK    64

typedef float        f32x4 __attribute__((ext_vector_type(4)));
typedef short        s16x8 __attribute__((ext_vector_type(8)));
typedef unsigned int u32x4 __attribute__((ext_vector_type(4)));

#define UR _Pragma("unroll")

__device__ __forceinline__ unsigned short f2bf(float f) {
    unsigned int u = __builtin_bit_cast(unsigned int, f);
    u = (u + 0x7fffu + ((u >> 16) & 1u)) >> 16;
    return (unsigned short)u;
}
__device__ __forceinline__ float bf2f(unsigned short h) {
    unsigned int u = ((unsigned int)h) << 16;
    return __builtin_bit_cast(float, u);
}
__device__ __forceinline__ unsigned int pack2(float lo, float hi) {
    return (unsigned int)f2bf(lo) | ((unsigned int)f2bf(hi) << 16);
}

// ---------------- fp32 -> bf16 pre-conversion
__global__ __launch_bounds__(256) void cvt_bf16_kernel(const float* __restrict__ in,
                                                       unsigned short* __restrict__ out,
                                                       int n8)
{
    int i = blockIdx.x * 256 + threadIdx.x;
    const int stride = gridDim.x * 256;
    for (; i < n8; i += stride) {
        const float* p = in + (size_t)i * 8;
        float4 a = *(const float4*)p;
        float4 b = *(const float4*)(p + 4);
        u32x4 v;
        v.x = pack2(a.x, a.y); v.y = pack2(a.z, a.w);
        v.z = pack2(b.x, b.y); v.w = pack2(b.z, b.w);
        *(u32x4*)(out + (size_t)i * 8) = v;
    }
}

// ---------------- Kernel A (R7-proven): k = RMSNorm(hid @ Wk^T)*k_norm_w -> kn_ws bf16 [S][1024]
__global__ __launch_bounds__(256) void kproj_bf16(const unsigned short* __restrict__ hid,
                                                  const unsigned short* __restrict__ Wk,
                                                  const float* __restrict__ knw,
                                                  unsigned short* __restrict__ kn_ws)
{
    __shared__ alignas(16) unsigned short smem[16896];
    __shared__ float rms_l[128];
    __shared__ float wsm[128];
    unsigned short (*qs)[132] = (unsigned short(*)[132])smem;

    const int tid = threadIdx.x, lane = tid & 63, wv = tid >> 6;
    const int wm = wv >> 1, wn = wv & 1;
    const int h = blockIdx.x, m0 = blockIdx.y * 128;
    if (tid < 128) wsm[tid] = knw[tid];

    const int lr = lane >> 3;
    const int lc = (((lane & 7) ^ lr) * 8);
    const int av0 = (wv * 32 + 0  + lr) * DIN + lc;
    const int av1 = (wv * 32 + 8  + lr) * DIN + lc;
    const int av2 = (wv * 32 + 16 + lr) * DIN + lc;
    const int av3 = (wv * 32 + 24 + lr) * DIN + lc;
    const int rA0 = (wm * 64 + (lane & 15)) * BK + ((lane >> 4) ^ (lane & 7)) * 8;
    const int rA1 = (wm * 64 + (lane & 15)) * BK + (((lane >> 4) + 4) ^ (lane & 7)) * 8;
    const int rB0 = (wn * 64 + (lane & 15)) * BK + ((lane >> 4) ^ (lane & 7)) * 8;
    const int rB1 = (wn * 64 + (lane & 15)) * BK + (((lane >> 4) + 4) ^ (lane & 7)) * 8;

    const unsigned short* aP = hid + (size_t)m0 * DIN;
    const unsigned short* bP = Wk + (size_t)h * DH * DIN;

    f32x4 acc[4][4];
    UR for (int m = 0; m < 4; ++m)
        UR for (int n = 0; n < 4; ++n)
            acc[m][n] = f32x4{0.f, 0.f, 0.f, 0.f};

    for (int kt = 0; kt < DIN; kt += BK) {
        UR for (int i = 0; i < 4; ++i) {
            const int ao = (i == 0) ? av0 : (i == 1) ? av1 : (i == 2) ? av2 : av3;
            __builtin_amdgcn_global_load_lds(
                (const __attribute__((address_space(1))) unsigned int*)(aP + ao),
                (__attribute__((address_space(3))) unsigned int*)(smem + (wv * 32 + i * 8) * BK), 16, 0, 0);
            __builtin_amdgcn_global_load_lds(
                (const __attribute__((address_space(1))) unsigned int*)(bP + ao),
                (__attribute__((address_space(3))) unsigned int*)(smem + 8192 + (wv * 32 + i * 8) * BK), 16, 0, 0);
        }
        __syncthreads();
        UR for (int kk = 0; kk < 2; ++kk) {
            const int sA = (kk ? rA1 : rA0);
            const int sB = 8192 + (kk ? rB1 : rB0);
            s16x8 af[4], bfr[4];
            UR for (int m = 0; m < 4; ++m) af[m] = *(const s16x8*)&smem[sA + m * 1024];
            UR for (int n = 0; n < 4; ++n) bfr[n] = *(const s16x8*)&smem[sB + n * 1024];
            UR for (int m = 0; m < 4; ++m)
                UR for (int n = 0; n < 4; ++n)
                    acc[m][n] = __builtin_amdgcn_mfma_f32_16x16x32_bf16(af[m], bfr[n], acc[m][n], 0, 0, 0);
        }
        __syncthreads();
        aP += BK; bP += BK;
    }

    UR for (int m = 0; m < 4; ++m)
        UR for (int n = 0; n < 4; ++n)
            UR for (int r = 0; r < 4; ++r)
                qs[wm * 64 + m * 16 + (lane >> 4) * 4 + r][wn * 64 + n * 16 + (lane & 15)] = f2bf(acc[m][n][r]);
    __syncthreads();
    if (tid < 128) {
        const unsigned short* row = qs[tid];
        float s2 = 0.f;
        UR for (int dw = 0; dw < 64; ++dw) {
            unsigned int v = *(const unsigned int*)&row[dw * 2];
            float f0 = bf2f((unsigned short)(v & 0xffff));
            float f1 = bf2f((unsigned short)(v >> 16));
            s2 += f0 * f0 + f1 * f1;
        }
        rms_l[tid] = rsqrtf(s2 * (1.0f / 128.0f) + 1e-6f);
    }
    __syncthreads();
    const int rloc = tid >> 4, cb = (tid & 15) * 8;
    UR for (int pass = 0; pass < 8; ++pass) {
        const int r = pass * 16 + rloc;
        const float rq = rms_l[r];
        u32x4 v;
        float f0, f1;
        f0 = bf2f(qs[r][cb + 0]) * rq * wsm[cb + 0];
        f1 = bf2f(qs[r][cb + 1]) * rq * wsm[cb + 1];
        v.x = pack2(f0, f1);
        f0 = bf2f(qs[r][cb + 2]) * rq * wsm[cb + 2];
        f1 = bf2f(qs[r][cb + 3]) * rq * wsm[cb + 3];
        v.y = pack2(f0, f1);
        f0 = bf2f(qs[r][cb + 4]) * rq * wsm[cb + 4];
        f1 = bf2f(qs[r][cb + 5]) * rq * wsm[cb + 5];
        v.z = pack2(f0, f1);
        f0 = bf2f(qs[r][cb + 6]) * rq * wsm[cb + 6];
        f1 = bf2f(qs[r][cb + 7]) * rq * wsm[cb + 7];
        v.w = pack2(f0, f1);
        *(u32x4*)&kn_ws[(size_t)(m0 + r) * (NH * DH) + h * DH + cb] = v;
    }
}

// ---------------- Kernel B: 256x256 tile, m201-faithful phases (reads BEFORE barrier,
// pure-MFMA clusters, counted vmcnt(4) with 4-phase slack) + MFMA sink gate.
//
// LDS per buffer (32768 elems): A = [2 kb][2 rowhalf][128 rows][4 slots x 8 bf16]
// (kb stride 8192, rowhalf stride 4096), B same at +16384. Additive slot swizzle:
// slot = (g + ((row>>1)&3)) & 3. Staged via pre-swizzled global source + linear LDS
// dest (rule #21).
//
// Per K-tile t (read R, stage next -> V), 4 phases x 16 MFMA:
//  Ph1: vmcnt(4); barrier          <- retires A(R,k0),B(R,k0) (issued 4 phases ago)
//       reads A(k0,h0)+B(k0) [8]; stage A(V,k0); barrier; lgkmcnt(0); MM(h0)
//  Ph2: reads A(k0,h1) [4];        stage B(V,k0); barrier; lgkmcnt(0); MM(h1)
//  Ph3: vmcnt(4|0 last); barrier   <- retires A(R,k1),B(R,k1)
//       reads A(k1,h0)+B(k1);      stage A(V,k1); barrier; lgkmcnt(0); MM(h0)
//  Ph4: reads A(k1,h1);            stage B(V,k1); barrier; lgkmcnt(0); MM(h1)
// ds_read latency hides under the straggler barrier + other waves' MFMA; loads are
// never drained mid-loop (steady 8 outstanding, vmcnt(4) keeps 4 in flight).
__global__ __launch_bounds__(512, 2) void qscore_bf16(const unsigned short* __restrict__ hid,
                                                      const unsigned short* __restrict__ Wq,
                                                      const float* __restrict__ bq,
                                                      const float* __restrict__ qnw,
                                                      const float* __restrict__ bb,
                                                      const float* __restrict__ kbase,
                                                      const unsigned short* __restrict__ kn_ws,
                                                      float* __restrict__ out)
{
    __shared__ alignas(16) unsigned short smem[65536];      // 2 x 64KB staging; qsc aliases after loop
    __shared__ alignas(16) unsigned short kbn[NSINK][136];  // bf16(k_base * q_norm_w)
    __shared__ float rms_l[256];
    __shared__ float l_l[256];
    __shared__ float wsm[128];
    unsigned short (*qsc)[132] = (unsigned short(*)[132])smem;  // per-chunk q tile, epilogue alias

    const int tid = threadIdx.x, lane = tid & 63, wv = tid >> 6;
    const int wm = wv >> 2, wn = wv & 3;           // 2M x 4N wave grid; wave owns 128x64
    const int nt = blockIdx.x;                     // n-tile 0..15
    const int m0 = blockIdx.y * 256;
    const int n0 = nt * 256;
    const int h  = nt >> 1;

    if (tid < 128) wsm[tid] = qnw[tid];
    if (tid < 256) {
        const int ts = tid >> 4, d0 = (tid & 15) * 8;
        const float* src = kbase + ((size_t)h * NSINK + ts) * DH + d0;
        float4 x = *(const float4*)src;
        float4 y = *(const float4*)(src + 4);
        const float* w = qnw + d0;
        u32x4 v;
        v.x = pack2(x.x * w[0], x.y * w[1]);
        v.y = pack2(x.z * w[2], x.w * w[3]);
        v.z = pack2(y.x * w[4], y.y * w[5]);
        v.w = pack2(y.z * w[6], y.w * w[7]);
        *(u32x4*)&kbn[ts][d0] = v;
    }

    // staging: thread -> LDS row tid>>2 (within 128-row half), slot tid&3;
    // fetched global granule g = (slot - ((row>>1)&3)) & 3 (inverse of additive swizzle)
    const int sg   = ((tid & 3) - ((tid >> 3) & 3)) & 3;
    const int sOff = (tid >> 2) * DIN + sg * 8;     // + kb*32 (+128*DIN for row-half 1)

    // fragment ds_read bases: slot = ((lane>>4) + ((l15>>1)&3)) & 3
    const int l15 = lane & 15;
    const int slt = ((lane >> 4) + ((l15 >> 1) & 3)) & 3;
    const int aB = wm * 4096 + l15 * 32 + slt * 8;          // + mf*512 + kb*8192
    const int bB = 16384 + wn * 2048 + l15 * 32 + slt * 8;  // + nf*512 + kb*8192

    const unsigned short* aStage = hid + (size_t)m0 * DIN;
    const unsigned short* bStage = Wq + (size_t)n0 * DIN;

    f32x4 acc[8][4];
    UR for (int m = 0; m < 8; ++m)
        UR for (int n = 0; n < 4; ++n)
            acc[m][n] = f32x4{0.f, 0.f, 0.f, 0.f};

    s16x8 aF[4], bF[4];

#define WAITV4 asm volatile("s_waitcnt vmcnt(4)" ::: "memory");
#define WAITV0 asm volatile("s_waitcnt vmcnt(0)" ::: "memory");
#define BARR   asm volatile("s_barrier" ::: "memory");
#define LGKM0  asm volatile("s_waitcnt lgkmcnt(0)" ::: "memory"); __builtin_amdgcn_sched_barrier(0);

#define STG1(DSTE, SRCP)                                                                           \
    __builtin_amdgcn_global_load_lds(                                                              \
        (const __attribute__((address_space(1))) unsigned int*)(SRCP),                             \
        (__attribute__((address_space(3))) unsigned int*)(smem + (DSTE) + tid * 8), 16, 0, 0);

#define STG_A(BUFW, KB)                                                                            \
    { STG1((BUFW) + (KB) * 8192,        aStage + sOff + (KB) * 32)                                 \
      STG1((BUFW) + (KB) * 8192 + 4096, aStage + sOff + (KB) * 32 + 128 * DIN) }

#define STG_B(BUFW, KB)                                                                            \
    { STG1((BUFW) + 16384 + (KB) * 8192,        bStage + sOff + (KB) * 32)                         \
      STG1((BUFW) + 16384 + (KB) * 8192 + 4096, bStage + sOff + (KB) * 32 + 128 * DIN) }

#define RDA(BUFR, KB, H)                                                                           \
    { UR for (int mf_ = 0; mf_ < 4; ++mf_)                                                         \
          aF[mf_] = *(const s16x8*)&smem[(BUFR) + (KB) * 8192 + aB + ((H) * 4 + mf_) * 512]; }

#define RDB(BUFR, KB)                                                                              \
    { UR for (int nf_ = 0; nf_ < 4; ++nf_)                                                         \
          bF[nf_] = *(const s16x8*)&smem[(BUFR) + (KB) * 8192 + bB + nf_ * 512]; }

#define MM(H)                                                                                      \
    { __builtin_amdgcn_s_setprio(1);                                                               \
      UR for (int mf_ = 0; mf_ < 4; ++mf_)                                                         \
          UR for (int nf_ = 0; nf_ < 4; ++nf_)                                                     \
              acc[(H) * 4 + mf_][nf_] = __builtin_amdgcn_mfma_f32_16x16x32_bf16(                   \
                  aF[mf_], bF[nf_], acc[(H) * 4 + mf_][nf_], 0, 0, 0);                             \
      __builtin_amdgcn_s_setprio(0); }

#define TILE(BUFR, BUFW, DOST, LASTT)                                                              \
    {                                                                                              \
        WAITV4 BARR                                                                                \
        RDA(BUFR, 0, 0) RDB(BUFR, 0)                                                               \
        if (DOST) STG_A(BUFW, 0)                                                                   \
        BARR LGKM0 MM(0)                                                                           \
        RDA(BUFR, 0, 1)                                                                            \
        if (DOST) STG_B(BUFW, 0)                                                                   \
        BARR LGKM0 MM(1)                                                                           \
        if (LASTT) { WAITV0 } else { WAITV4 }                                                      \
        BARR                                                                                       \
        RDA(BUFR, 1, 0) RDB(BUFR, 1)                                                               \
        if (DOST) STG_A(BUFW, 1)                                                                   \
        BARR LGKM0 MM(0)                                                                           \
        RDA(BUFR, 1, 1)                                                                            \
        if (DOST) STG_B(BUFW, 1)                                                                   \
        BARR LGKM0 MM(1)                                                                           \
        if (DOST) { aStage += BK; bStage += BK; }                                                  \
    }

    // prologue: stage tile 0 into buf0 in ledger order {A k0, B k0, A k1, B k1}
    STG_A(0, 0) STG_B(0, 0) STG_A(0, 1) STG_B(0, 1)
    aStage += BK; bStage += BK;

    for (int i = 0; i < 15; ++i) {
        TILE(0, 32768, 1, 0)     // even tile reads buf0, stages -> buf1
        TILE(32768, 0, 1, 0)     // odd tile reads buf1, stages -> buf0
    }
    TILE(0, 32768, 1, 0)         // t=30 (stages t=31 -> buf1)
    TILE(32768, 0, 0, 1)         // t=31: no staging; Ph3 drains vmcnt(0)

#undef WAITV4
#undef WAITV0
#undef BARR
#undef LGKM0
#undef STG1
#undef STG_A
#undef STG_B
#undef RDA
#undef RDB
#undef MM
#undef TILE

    __syncthreads();             // staging buffers dead; qsc alias becomes writable

    // ---- epilogue: two chunk-rounds (chunk c = cols c*128..+127 of the 256-wide tile)
    float bqv[4];
    UR for (int nf = 0; nf < 4; ++nf)
        bqv[nf] = bq[n0 + wn * 64 + nf * 16 + l15];

    for (int c = 0; c < 2; ++c) {
        if (((wv >> 1) & 1) == c) {
            UR for (int mf = 0; mf < 8; ++mf)
                UR for (int nf = 0; nf < 4; ++nf)
                    UR for (int r = 0; r < 4; ++r)
                        qsc[wm * 128 + mf * 16 + (lane >> 4) * 4 + r][(wv & 1) * 64 + nf * 16 + l15] =
                            f2bf(acc[mf][nf][r] + bqv[nf]);
        }
        __syncthreads();

        const float bvalc = 2.0f * bb[h * NG + ((nt * 2 + c) & 3)];
        // pass2: 2 threads per row; rms + k.q logit (k from L2-resident kn_ws)
        {
            const int r2 = tid >> 1, ch = (tid & 1) * 64;
            const unsigned short* qrow = &qsc[r2][ch];
            const unsigned short* kg = kn_ws + (size_t)(m0 + r2) * (NH * DH) + h * DH + ch;
            const float* wp = &wsm[ch];
            float s2 = 0.f, skq = 0.f;
            UR for (int i = 0; i < 8; ++i) {
                u32x4 kv = *(const u32x4*)(kg + i * 8);
                UR for (int j = 0; j < 4; ++j) {
                    unsigned int qv = *(const unsigned int*)&qrow[i * 8 + j * 2];
                    unsigned int kw = kv[j];
                    float q0 = bf2f((unsigned short)(qv & 0xffff));
                    float q1 = bf2f((unsigned short)(qv >> 16));
                    float k0 = bf2f((unsigned short)(kw & 0xffff));
                    float k1 = bf2f((unsigned short)(kw >> 16));
                    s2  += q0 * q0 + q1 * q1;
                    skq += q0 * k0 * wp[i * 8 + j * 2] + q1 * k1 * wp[i * 8 + j * 2 + 1];
                }
            }
            s2  += __shfl_xor(s2, 1);
            skq += __shfl_xor(skq, 1);
            if ((tid & 1) == 0) {
                const float rs = rsqrtf(s2 * (1.0f / 128.0f) + 1e-6f) * 0.08838834764831845f;
                rms_l[r2] = rs;
                l_l[r2]   = skq * rs + bvalc;
            }
        }
        __syncthreads();

        // pass3 (MFMA): sink logits; wave wv owns rows [wv*32, wv*32+32)
        {
            f32x4 sacc0 = f32x4{0.f, 0.f, 0.f, 0.f};
            f32x4 sacc1 = f32x4{0.f, 0.f, 0.f, 0.f};
            const int ar = wv * 32 + l15;
            const int kc = (lane >> 4) * 8;
            UR for (int ks = 0; ks < 4; ++ks) {
                s16x8 bf_ = *(const s16x8*)&kbn[l15][ks * 32 + kc];
                s16x8 a0  = *(const s16x8*)&qsc[ar][ks * 32 + kc];
                s16x8 a1  = *(const s16x8*)&qsc[ar + 16][ks * 32 + kc];
                sacc0 = __builtin_amdgcn_mfma_f32_16x16x32_bf16(a0, bf_, sacc0, 0, 0, 0);
                sacc1 = __builtin_amdgcn_mfma_f32_16x16x32_bf16(a1, bf_, sacc1, 0, 0, 0);
            }
            UR for (int mt = 0; mt < 2; ++mt) {
                f32x4 sa = mt ? sacc1 : sacc0;
                UR for (int r = 0; r < 4; ++r) {
                    const int row = wv * 32 + mt * 16 + (lane >> 4) * 4 + r;
                    float e = __expf(sa[r] * rms_l[row] - l_l[row]);
                    e += __shfl_xor(e, 1);
                    e += __shfl_xor(e, 2);
                    e += __shfl_xor(e, 4);
                    e += __shfl_xor(e, 8);
                    if (l15 == 0)
                        atomicAdd(&out[(size_t)h * S_TOK + m0 + row], 0.25f / (1.0f + e));
                }
            }
        }
        __syncthreads();   // before next round overwrites qsc
    }
}

extern "C" void kernel_launch(void* const* d_in, const int* in_sizes, int n_in,
                              void* d_out, int out_size, void* d_ws, size_t ws_size,
                              hipStream_t stream)
{
    const float* hid = (const float*)d_in[0];
    const float* Wq  = (const float*)d_in[1];
    const float* bq  = (const float*)d_in[2];
    const float* Wk  = (const float*)d_in[3];
    const float* qnw = (const float*)d_in[4];
    const float* knw = (const float*)d_in[5];
    const float* bb  = (const float*)d_in[6];
    const float* kb  = (const float*)d_in[7];
    float* out = (float*)d_out;

    (void)hipMemsetAsync(d_out, 0, (size_t)out_size * sizeof(float), stream);

    const size_t HID_E = (size_t)S_TOK * DIN;
    const size_t WQ_E  = (size_t)NH * NG * DH * DIN;
    const size_t WK_E  = (size_t)NH * DH * DIN;

    unsigned short* hid_b = (unsigned short*)d_ws;
    unsigned short* wq_b  = hid_b + HID_E;
    unsigned short* wk_b  = wq_b + WQ_E;
    unsigned short* kn_ws = wk_b + WK_E;

    cvt_bf16_kernel<<<2048, 256, 0, stream>>>(hid, hid_b, (int)(HID_E / 8));
    cvt_bf16_kernel<<<512, 256, 0, stream>>>(Wq, wq_b, (int)(WQ_E / 8));
    cvt_bf16_kernel<<<256, 256, 0, stream>>>(Wk, wk_b, (int)(WK_E / 8));

    kproj_bf16<<<dim3(NH, S_TOK / 128), dim3(256), 0, stream>>>(hid_b, wk_b, knw, kn_ws);
    qscore_bf16<<<dim3(NH * NG / 2, S_TOK / 256), dim3(512), 0, stream>>>(hid_b, wq_b, bq, qnw, bb, kb, kn_ws, out);
}

// Round 12
// 782.302 us; speedup vs baseline: 1.0727x; 1.0727x over previous
//
#include <hip/hip_runtime.h>

#define S_TOK 32768
#define DIN   2048
#define NH    8
#define NG    4
#define DH    128
#define NSINK 16
#define BK    64

typedef float        f32x4 __attribute__((ext_vector_type(4)));
typedef short        s16x8 __attribute__((ext_vector_type(8)));
typedef unsigned int u32x4 __attribute__((ext_vector_type(4)));

#define UR _Pragma("unroll")

__device__ __forceinline__ unsigned short f2bf(float f) {
    unsigned int u = __builtin_bit_cast(unsigned int, f);
    u = (u + 0x7fffu + ((u >> 16) & 1u)) >> 16;
    return (unsigned short)u;
}
__device__ __forceinline__ float bf2f(unsigned short h) {
    unsigned int u = ((unsigned int)h) << 16;
    return __builtin_bit_cast(float, u);
}
__device__ __forceinline__ unsigned int pack2(float lo, float hi) {
    return (unsigned int)f2bf(lo) | ((unsigned int)f2bf(hi) << 16);
}

// ---------------- fused fp32 -> bf16 pre-conversion (3 segments, 1 launch)
// blocks [0,2048): hid (16 iters) | [2048,2560): Wq (8 iters) | [2560,2816): Wk (4 iters)
__global__ __launch_bounds__(256) void cvt_all_kernel(const float* __restrict__ hid,
                                                      const float* __restrict__ wq,
                                                      const float* __restrict__ wk,
                                                      unsigned short* __restrict__ ohid,
                                                      unsigned short* __restrict__ owq,
                                                      unsigned short* __restrict__ owk)
{
    const float* in;
    unsigned short* out;
    int n8, i, stride;
    if (blockIdx.x < 2048) {
        in = hid; out = ohid; n8 = (S_TOK * DIN) / 8;
        i = blockIdx.x * 256 + threadIdx.x; stride = 2048 * 256;
    } else if (blockIdx.x < 2560) {
        in = wq; out = owq; n8 = (NH * NG * DH * DIN) / 8;
        i = (blockIdx.x - 2048) * 256 + threadIdx.x; stride = 512 * 256;
    } else {
        in = wk; out = owk; n8 = (NH * DH * DIN) / 8;
        i = (blockIdx.x - 2560) * 256 + threadIdx.x; stride = 256 * 256;
    }
    for (; i < n8; i += stride) {
        const float* p = in + (size_t)i * 8;
        float4 a = *(const float4*)p;
        float4 b = *(const float4*)(p + 4);
        u32x4 v;
        v.x = pack2(a.x, a.y); v.y = pack2(a.z, a.w);
        v.z = pack2(b.x, b.y); v.w = pack2(b.z, b.w);
        *(u32x4*)(out + (size_t)i * 8) = v;
    }
}

// ---------------- Kernel A (R7-proven): k = RMSNorm(hid @ Wk^T)*k_norm_w -> kn_ws bf16 [S][1024]
__global__ __launch_bounds__(256) void kproj_bf16(const unsigned short* __restrict__ hid,
                                                  const unsigned short* __restrict__ Wk,
                                                  const float* __restrict__ knw,
                                                  unsigned short* __restrict__ kn_ws)
{
    __shared__ alignas(16) unsigned short smem[16896];
    __shared__ float rms_l[128];
    __shared__ float wsm[128];
    unsigned short (*qs)[132] = (unsigned short(*)[132])smem;

    const int tid = threadIdx.x, lane = tid & 63, wv = tid >> 6;
    const int wm = wv >> 1, wn = wv & 1;
    const int h = blockIdx.x, m0 = blockIdx.y * 128;
    if (tid < 128) wsm[tid] = knw[tid];

    const int lr = lane >> 3;
    const int lc = (((lane & 7) ^ lr) * 8);
    const int av0 = (wv * 32 + 0  + lr) * DIN + lc;
    const int av1 = (wv * 32 + 8  + lr) * DIN + lc;
    const int av2 = (wv * 32 + 16 + lr) * DIN + lc;
    const int av3 = (wv * 32 + 24 + lr) * DIN + lc;
    const int rA0 = (wm * 64 + (lane & 15)) * BK + ((lane >> 4) ^ (lane & 7)) * 8;
    const int rA1 = (wm * 64 + (lane & 15)) * BK + (((lane >> 4) + 4) ^ (lane & 7)) * 8;
    const int rB0 = (wn * 64 + (lane & 15)) * BK + ((lane >> 4) ^ (lane & 7)) * 8;
    const int rB1 = (wn * 64 + (lane & 15)) * BK + (((lane >> 4) + 4) ^ (lane & 7)) * 8;

    const unsigned short* aP = hid + (size_t)m0 * DIN;
    const unsigned short* bP = Wk + (size_t)h * DH * DIN;

    f32x4 acc[4][4];
    UR for (int m = 0; m < 4; ++m)
        UR for (int n = 0; n < 4; ++n)
            acc[m][n] = f32x4{0.f, 0.f, 0.f, 0.f};

    for (int kt = 0; kt < DIN; kt += BK) {
        UR for (int i = 0; i < 4; ++i) {
            const int ao = (i == 0) ? av0 : (i == 1) ? av1 : (i == 2) ? av2 : av3;
            __builtin_amdgcn_global_load_lds(
                (const __attribute__((address_space(1))) unsigned int*)(aP + ao),
                (__attribute__((address_space(3))) unsigned int*)(smem + (wv * 32 + i * 8) * BK), 16, 0, 0);
            __builtin_amdgcn_global_load_lds(
                (const __attribute__((address_space(1))) unsigned int*)(bP + ao),
                (__attribute__((address_space(3))) unsigned int*)(smem + 8192 + (wv * 32 + i * 8) * BK), 16, 0, 0);
        }
        __syncthreads();
        UR for (int kk = 0; kk < 2; ++kk) {
            const int sA = (kk ? rA1 : rA0);
            const int sB = 8192 + (kk ? rB1 : rB0);
            s16x8 af[4], bfr[4];
            UR for (int m = 0; m < 4; ++m) af[m] = *(const s16x8*)&smem[sA + m * 1024];
            UR for (int n = 0; n < 4; ++n) bfr[n] = *(const s16x8*)&smem[sB + n * 1024];
            UR for (int m = 0; m < 4; ++m)
                UR for (int n = 0; n < 4; ++n)
                    acc[m][n] = __builtin_amdgcn_mfma_f32_16x16x32_bf16(af[m], bfr[n], acc[m][n], 0, 0, 0);
        }
        __syncthreads();
        aP += BK; bP += BK;
    }

    UR for (int m = 0; m < 4; ++m)
        UR for (int n = 0; n < 4; ++n)
            UR for (int r = 0; r < 4; ++r)
                qs[wm * 64 + m * 16 + (lane >> 4) * 4 + r][wn * 64 + n * 16 + (lane & 15)] = f2bf(acc[m][n][r]);
    __syncthreads();
    if (tid < 128) {
        const unsigned short* row = qs[tid];
        float s2 = 0.f;
        UR for (int dw = 0; dw < 64; ++dw) {
            unsigned int v = *(const unsigned int*)&row[dw * 2];
            float f0 = bf2f((unsigned short)(v & 0xffff));
            float f1 = bf2f((unsigned short)(v >> 16));
            s2 += f0 * f0 + f1 * f1;
        }
        rms_l[tid] = rsqrtf(s2 * (1.0f / 128.0f) + 1e-6f);
    }
    __syncthreads();
    const int rloc = tid >> 4, cb = (tid & 15) * 8;
    UR for (int pass = 0; pass < 8; ++pass) {
        const int r = pass * 16 + rloc;
        const float rq = rms_l[r];
        u32x4 v;
        float f0, f1;
        f0 = bf2f(qs[r][cb + 0]) * rq * wsm[cb + 0];
        f1 = bf2f(qs[r][cb + 1]) * rq * wsm[cb + 1];
        v.x = pack2(f0, f1);
        f0 = bf2f(qs[r][cb + 2]) * rq * wsm[cb + 2];
        f1 = bf2f(qs[r][cb + 3]) * rq * wsm[cb + 3];
        v.y = pack2(f0, f1);
        f0 = bf2f(qs[r][cb + 4]) * rq * wsm[cb + 4];
        f1 = bf2f(qs[r][cb + 5]) * rq * wsm[cb + 5];
        v.z = pack2(f0, f1);
        f0 = bf2f(qs[r][cb + 6]) * rq * wsm[cb + 6];
        f1 = bf2f(qs[r][cb + 7]) * rq * wsm[cb + 7];
        v.w = pack2(f0, f1);
        *(u32x4*)&kn_ws[(size_t)(m0 + r) * (NH * DH) + h * DH + cb] = v;
    }
}

// ---------------- Kernel B (R8-proven): 256x256-tile deep-pipelined q-proj + RMSNorm + MFMA sink gate
// LDS buffer (32768 elems each): A[256][64] at +0 (halves at 0/8192), B[256][64] at +16384.
// Granule slot s of row r stores global granule s^(r&7); read slot = g^(r&7).
// Schedule per K-tile: stage ALL of tile t+1 (8 global_load_lds) at tile start into the
// other buffer, 64 MFMA + 24 ds_read in one region, then ONE vmcnt(0)+s_barrier.
// (R9-R11 finer-grained variants all regressed: with 8 waves and 1 block/CU, added
// barrier straggler-jitter exceeds the single per-tile drain. This coarse schedule is
// the measured optimum of the 4 variants benched.)
__global__ __launch_bounds__(512, 2) void qscore_bf16(const unsigned short* __restrict__ hid,
                                                      const unsigned short* __restrict__ Wq,
                                                      const float* __restrict__ bq,
                                                      const float* __restrict__ qnw,
                                                      const float* __restrict__ bb,
                                                      const float* __restrict__ kbase,
                                                      const unsigned short* __restrict__ kn_ws,
                                                      float* __restrict__ out)
{
    __shared__ alignas(16) unsigned short smem[65536];      // 2 x 64KB staging; qsc aliases after loop
    __shared__ alignas(16) unsigned short kbn[NSINK][136];  // bf16(k_base * q_norm_w)
    __shared__ float rms_l[256];
    __shared__ float l_l[256];
    __shared__ float wsm[128];
    unsigned short (*qsc)[132] = (unsigned short(*)[132])smem;  // per-chunk q tile, epilogue alias

    const int tid = threadIdx.x, lane = tid & 63, wv = tid >> 6;
    const int wm = wv >> 2, wn = wv & 3;           // 2M x 4N wave grid; wave owns 128x64
    const int nt = blockIdx.x;                     // n-tile 0..15 (fast: shares A across L2)
    const int m0 = blockIdx.y * 256;
    const int n0 = nt * 256;
    const int h  = nt >> 1;                        // both chunks of this tile share one head

    if (tid < 128) wsm[tid] = qnw[tid];
    if (tid < 256) {
        const int ts = tid >> 4, d0 = (tid & 15) * 8;
        const float* src = kbase + ((size_t)h * NSINK + ts) * DH + d0;
        float4 x = *(const float4*)src;
        float4 y = *(const float4*)(src + 4);
        const float* w = qnw + d0;
        u32x4 v;
        v.x = pack2(x.x * w[0], x.y * w[1]);
        v.y = pack2(x.z * w[2], x.w * w[3]);
        v.z = pack2(y.x * w[4], y.y * w[5]);
        v.w = pack2(y.z * w[6], y.w * w[7]);
        *(u32x4*)&kbn[ts][d0] = v;
    }

    // staging source offset (per-thread): granule index = tid (j=0) / tid+512 (j=1)
    const int srow = tid >> 3;
    const int so0 = srow * DIN + (((tid & 7) ^ (srow & 7)) * 8);   // j=1 adds 64*DIN, lds +4096

    // fragment ds_read offsets (row&7 == lane&7 for all frags since frag rows are 16-aligned)
    const int l15 = lane & 15;
    const int slotA = ((lane >> 4) ^ (lane & 7)) * 8;
    const int aOff0 = (wm * 128 + l15) * 64 + slotA;
    const int aOff1 = aOff0 ^ 32;                  // kk=1: slot^4 -> elem offset ^32
    const int bOff0 = (wn * 64 + l15) * 64 + slotA;
    const int bOff1 = bOff0 ^ 32;

    const unsigned short* aStage = hid + (size_t)m0 * DIN;
    const unsigned short* bStage = Wq + (size_t)n0 * DIN;

    f32x4 acc[8][4];
    UR for (int m = 0; m < 8; ++m)
        UR for (int n = 0; n < 4; ++n)
            acc[m][n] = f32x4{0.f, 0.f, 0.f, 0.f};

    s16x8 aF[4][2], bF[4][2];

#define GL(LDSB, SRC)                                                                              \
    __builtin_amdgcn_global_load_lds(                                                              \
        (const __attribute__((address_space(1))) unsigned int*)((SRC) + so0),                      \
        (__attribute__((address_space(3))) unsigned int*)(smem + (LDSB) + tid * 8), 16, 0, 0);     \
    __builtin_amdgcn_global_load_lds(                                                              \
        (const __attribute__((address_space(1))) unsigned int*)((SRC) + so0 + 64 * DIN),           \
        (__attribute__((address_space(3))) unsigned int*)(smem + (LDSB) + 4096 + tid * 8), 16, 0, 0);

#define GLALL(BUFW)                                                                                \
    { GL((BUFW) + 0,     aStage)             GL((BUFW) + 8192,  aStage + 128 * DIN)                \
      GL((BUFW) + 16384, bStage)             GL((BUFW) + 24576, bStage + 128 * DIN) }

#define LDA(BUF, QH)                                                                               \
    { UR for (int i_ = 0; i_ < 4; ++i_) {                                                          \
        aF[i_][0] = *(const s16x8*)&smem[(BUF) + aOff0 + ((QH) * 4 + i_) * 1024];                  \
        aF[i_][1] = *(const s16x8*)&smem[(BUF) + aOff1 + ((QH) * 4 + i_) * 1024]; } }

#define LDB(BUF, NH2)                                                                              \
    { UR for (int j_ = 0; j_ < 2; ++j_) {                                                          \
        bF[(NH2) * 2 + j_][0] = *(const s16x8*)&smem[(BUF) + 16384 + bOff0 + ((NH2) * 2 + j_) * 1024]; \
        bF[(NH2) * 2 + j_][1] = *(const s16x8*)&smem[(BUF) + 16384 + bOff1 + ((NH2) * 2 + j_) * 1024]; } }

#define MFMAQ(MF0, NF0)                                                                            \
    { __builtin_amdgcn_s_setprio(1);                                                               \
      UR for (int i_ = 0; i_ < 4; ++i_)                                                            \
        UR for (int j_ = 0; j_ < 2; ++j_)                                                          \
          UR for (int k_ = 0; k_ < 2; ++k_)                                                        \
            acc[(MF0) + i_][(NF0) + j_] = __builtin_amdgcn_mfma_f32_16x16x32_bf16(                 \
                aF[i_][k_], bF[(NF0) + j_][k_], acc[(MF0) + i_][(NF0) + j_], 0, 0, 0);             \
      __builtin_amdgcn_s_setprio(0); }

#define TILE(BUFR, BUFW, DOSTAGE)                                                                  \
    {                                                                                              \
        LDA(BUFR, 0); LDB(BUFR, 0);                                                                \
        if (DOSTAGE) { GLALL(BUFW); aStage += BK; bStage += BK; }                                  \
        MFMAQ(0, 0);                                                                               \
        LDB(BUFR, 1);                                                                              \
        MFMAQ(0, 2);                                                                               \
        LDA(BUFR, 1);                                                                              \
        MFMAQ(4, 2);                                                                               \
        MFMAQ(4, 0);                                                                               \
        asm volatile("s_waitcnt vmcnt(0)" ::: "memory");                                           \
        asm volatile("s_barrier" ::: "memory");                                                    \
    }

    // prologue: stage tile 0 -> buf0, drain, barrier
    GLALL(0)
    aStage += BK; bStage += BK;
    asm volatile("s_waitcnt vmcnt(0)" ::: "memory");
    asm volatile("s_barrier" ::: "memory");

    for (int i = 0; i < 15; ++i) {
        TILE(0, 32768, 1);       // even tile: read buf0, stage next -> buf1
        TILE(32768, 0, 1);       // odd tile: read buf1, stage next -> buf0
    }
    TILE(0, 32768, 1);           // tile 30 (stages tile 31)
    TILE(32768, 0, 0);           // tile 31 (no staging)

#undef GL
#undef GLALL
#undef LDA
#undef LDB
#undef MFMAQ
#undef TILE

    // ---- epilogue: two chunk-rounds (chunk c = cols c*128..c*128+127 of the 256-wide tile)
    float bqv[4];
    UR for (int nf = 0; nf < 4; ++nf)
        bqv[nf] = bq[n0 + wn * 64 + nf * 16 + l15];

    for (int c = 0; c < 2; ++c) {
        if (((wv >> 1) & 1) == c) {
            UR for (int mf = 0; mf < 8; ++mf)
                UR for (int nf = 0; nf < 4; ++nf)
                    UR for (int r = 0; r < 4; ++r)
                        qsc[wm * 128 + mf * 16 + (lane >> 4) * 4 + r][(wv & 1) * 64 + nf * 16 + l15] =
                            f2bf(acc[mf][nf][r] + bqv[nf]);
        }
        __syncthreads();

        const float bvalc = 2.0f * bb[h * NG + ((nt * 2 + c) & 3)];
        // pass2: 2 threads per row; rms + k.q logit (k from L2-resident kn_ws)
        {
            const int r2 = tid >> 1, ch = (tid & 1) * 64;
            const unsigned short* qrow = &qsc[r2][ch];
            const unsigned short* kg = kn_ws + (size_t)(m0 + r2) * (NH * DH) + h * DH + ch;
            const float* wp = &wsm[ch];
            float s2 = 0.f, skq = 0.f;
            UR for (int i = 0; i < 8; ++i) {
                u32x4 kv = *(const u32x4*)(kg + i * 8);
                UR for (int j = 0; j < 4; ++j) {
                    unsigned int qv = *(const unsigned int*)&qrow[i * 8 + j * 2];
                    unsigned int kw = kv[j];
                    float q0 = bf2f((unsigned short)(qv & 0xffff));
                    float q1 = bf2f((unsigned short)(qv >> 16));
                    float k0 = bf2f((unsigned short)(kw & 0xffff));
                    float k1 = bf2f((unsigned short)(kw >> 16));
                    s2  += q0 * q0 + q1 * q1;
                    skq += q0 * k0 * wp[i * 8 + j * 2] + q1 * k1 * wp[i * 8 + j * 2 + 1];
                }
            }
            s2  += __shfl_xor(s2, 1);
            skq += __shfl_xor(skq, 1);
            if ((tid & 1) == 0) {
                const float rs = rsqrtf(s2 * (1.0f / 128.0f) + 1e-6f) * 0.08838834764831845f;
                rms_l[r2] = rs;
                l_l[r2]   = skq * rs + bvalc;
            }
        }
        __syncthreads();

        // pass3 (MFMA): sink logits; wave wv owns rows [wv*32, wv*32+32)
        {
            f32x4 sacc0 = f32x4{0.f, 0.f, 0.f, 0.f};
            f32x4 sacc1 = f32x4{0.f, 0.f, 0.f, 0.f};
            const int ar = wv * 32 + l15;
            const int kc = (lane >> 4) * 8;
            UR for (int ks = 0; ks < 4; ++ks) {
                s16x8 bf_ = *(const s16x8*)&kbn[l15][ks * 32 + kc];
                s16x8 a0  = *(const s16x8*)&qsc[ar][ks * 32 + kc];
                s16x8 a1  = *(const s16x8*)&qsc[ar + 16][ks * 32 + kc];
                sacc0 = __builtin_amdgcn_mfma_f32_16x16x32_bf16(a0, bf_, sacc0, 0, 0, 0);
                sacc1 = __builtin_amdgcn_mfma_f32_16x16x32_bf16(a1, bf_, sacc1, 0, 0, 0);
            }
            UR for (int mt = 0; mt < 2; ++mt) {
                f32x4 sa = mt ? sacc1 : sacc0;
                UR for (int r = 0; r < 4; ++r) {
                    const int row = wv * 32 + mt * 16 + (lane >> 4) * 4 + r;
                    float e = __expf(sa[r] * rms_l[row] - l_l[row]);
                    e += __shfl_xor(e, 1);
                    e += __shfl_xor(e, 2);
                    e += __shfl_xor(e, 4);
                    e += __shfl_xor(e, 8);
                    if (l15 == 0)
                        atomicAdd(&out[(size_t)h * S_TOK + m0 + row], 0.25f / (1.0f + e));
                }
            }
        }
        __syncthreads();   // before next round overwrites qsc
    }
}

extern "C" void kernel_launch(void* const* d_in, const int* in_sizes, int n_in,
                              void* d_out, int out_size, void* d_ws, size_t ws_size,
                              hipStream_t stream)
{
    const float* hid = (const float*)d_in[0];
    const float* Wq  = (const float*)d_in[1];
    const float* bq  = (const float*)d_in[2];
    const float* Wk  = (const float*)d_in[3];
    const float* qnw = (const float*)d_in[4];
    const float* knw = (const float*)d_in[5];
    const float* bb  = (const float*)d_in[6];
    const float* kb  = (const float*)d_in[7];
    float* out = (float*)d_out;

    (void)hipMemsetAsync(d_out, 0, (size_t)out_size * sizeof(float), stream);

    const size_t HID_E = (size_t)S_TOK * DIN;
    const size_t WQ_E  = (size_t)NH * NG * DH * DIN;
    const size_t WK_E  = (size_t)NH * DH * DIN;

    unsigned short* hid_b = (unsigned short*)d_ws;
    unsigned short* wq_b  = hid_b + HID_E;
    unsigned short* wk_b  = wq_b + WQ_E;
    unsigned short* kn_ws = wk_b + WK_E;

    cvt_all_kernel<<<2816, 256, 0, stream>>>(hid, Wq, Wk, hid_b, wq_b, wk_b);

    kproj_bf16<<<dim3(NH, S_TOK / 128), dim3(256), 0, stream>>>(hid_b, wk_b, knw, kn_ws);
    qscore_bf16<<<dim3(NH * NG / 2, S_TOK / 256), dim3(512), 0, stream>>>(hid_b, wq_b, bq, qnw, bb, kb, kn_ws, out);
}

// Round 13
// 748.441 us; speedup vs baseline: 1.1213x; 1.0452x over previous
//
#include <hip/hip_runtime.h>

#define S_TOK 32768
#define DIN   2048
#define NH    8
#define NG    4
#define DH    128
#define NSINK 16
#define BK    64

typedef float        f32x4 __attribute__((ext_vector_type(4)));
typedef short        s16x8 __attribute__((ext_vector_type(8)));
typedef unsigned int u32x4 __attribute__((ext_vector_type(4)));

#define UR _Pragma("unroll")

__device__ __forceinline__ unsigned short f2bf(float f) {
    unsigned int u = __builtin_bit_cast(unsigned int, f);
    u = (u + 0x7fffu + ((u >> 16) & 1u)) >> 16;
    return (unsigned short)u;
}
__device__ __forceinline__ float bf2f(unsigned short h) {
    unsigned int u = ((unsigned int)h) << 16;
    return __builtin_bit_cast(float, u);
}
__device__ __forceinline__ unsigned int pack2(float lo, float hi) {
    return (unsigned int)f2bf(lo) | ((unsigned int)f2bf(hi) << 16);
}

// ---------------- fused fp32 -> bf16 pre-conversion (3 segments, 1 launch)
__global__ __launch_bounds__(256) void cvt_all_kernel(const float* __restrict__ hid,
                                                      const float* __restrict__ wq,
                                                      const float* __restrict__ wk,
                                                      unsigned short* __restrict__ ohid,
                                                      unsigned short* __restrict__ owq,
                                                      unsigned short* __restrict__ owk)
{
    const float* in;
    unsigned short* out;
    int n8, i, stride;
    if (blockIdx.x < 2048) {
        in = hid; out = ohid; n8 = (S_TOK * DIN) / 8;
        i = blockIdx.x * 256 + threadIdx.x; stride = 2048 * 256;
    } else if (blockIdx.x < 2560) {
        in = wq; out = owq; n8 = (NH * NG * DH * DIN) / 8;
        i = (blockIdx.x - 2048) * 256 + threadIdx.x; stride = 512 * 256;
    } else {
        in = wk; out = owk; n8 = (NH * DH * DIN) / 8;
        i = (blockIdx.x - 2560) * 256 + threadIdx.x; stride = 256 * 256;
    }
    for (; i < n8; i += stride) {
        const float* p = in + (size_t)i * 8;
        float4 a = *(const float4*)p;
        float4 b = *(const float4*)(p + 4);
        u32x4 v;
        v.x = pack2(a.x, a.y); v.y = pack2(a.z, a.w);
        v.z = pack2(b.x, b.y); v.w = pack2(b.z, b.w);
        *(u32x4*)(out + (size_t)i * 8) = v;
    }
}

// ---------------- Kernel A (R8-structure): k = RMSNorm(hid @ Wk^T)*k_norm_w -> kn_ws bf16 [S][1024]
// 256x256 tile over N=1024 (all 8 heads; chunk of 128 cols == one head's full D).
// Main K-loop is byte-identical to qscore's proven coarse pipeline.
__global__ __launch_bounds__(512, 2) void kproj256_bf16(const unsigned short* __restrict__ hid,
                                                        const unsigned short* __restrict__ Wk,
                                                        const float* __restrict__ knw,
                                                        unsigned short* __restrict__ kn_ws)
{
    __shared__ alignas(16) unsigned short smem[65536];      // 2 x 64KB staging; qsc aliases after loop
    __shared__ float wsm[128];
    unsigned short (*qsc)[132] = (unsigned short(*)[132])smem;

    const int tid = threadIdx.x, lane = tid & 63, wv = tid >> 6;
    const int wm = wv >> 2, wn = wv & 3;
    const int nt = blockIdx.x;                     // 0..3 (cols nt*256..+255 = heads 2nt, 2nt+1)
    const int m0 = blockIdx.y * 256;
    const int n0 = nt * 256;

    if (tid < 128) wsm[tid] = knw[tid];

    const int srow = tid >> 3;
    const int so0 = srow * DIN + (((tid & 7) ^ (srow & 7)) * 8);

    const int l15 = lane & 15;
    const int slotA = ((lane >> 4) ^ (lane & 7)) * 8;
    const int aOff0 = (wm * 128 + l15) * 64 + slotA;
    const int aOff1 = aOff0 ^ 32;
    const int bOff0 = (wn * 64 + l15) * 64 + slotA;
    const int bOff1 = bOff0 ^ 32;

    const unsigned short* aStage = hid + (size_t)m0 * DIN;
    const unsigned short* bStage = Wk + (size_t)n0 * DIN;

    f32x4 acc[8][4];
    UR for (int m = 0; m < 8; ++m)
        UR for (int n = 0; n < 4; ++n)
            acc[m][n] = f32x4{0.f, 0.f, 0.f, 0.f};

    s16x8 aF[4][2], bF[4][2];

#define GL(LDSB, SRC)                                                                              \
    __builtin_amdgcn_global_load_lds(                                                              \
        (const __attribute__((address_space(1))) unsigned int*)((SRC) + so0),                      \
        (__attribute__((address_space(3))) unsigned int*)(smem + (LDSB) + tid * 8), 16, 0, 0);     \
    __builtin_amdgcn_global_load_lds(                                                              \
        (const __attribute__((address_space(1))) unsigned int*)((SRC) + so0 + 64 * DIN),           \
        (__attribute__((address_space(3))) unsigned int*)(smem + (LDSB) + 4096 + tid * 8), 16, 0, 0);

#define GLALL(BUFW)                                                                                \
    { GL((BUFW) + 0,     aStage)             GL((BUFW) + 8192,  aStage + 128 * DIN)                \
      GL((BUFW) + 16384, bStage)             GL((BUFW) + 24576, bStage + 128 * DIN) }

#define LDA(BUF, QH)                                                                               \
    { UR for (int i_ = 0; i_ < 4; ++i_) {                                                          \
        aF[i_][0] = *(const s16x8*)&smem[(BUF) + aOff0 + ((QH) * 4 + i_) * 1024];                  \
        aF[i_][1] = *(const s16x8*)&smem[(BUF) + aOff1 + ((QH) * 4 + i_) * 1024]; } }

#define LDB(BUF, NH2)                                                                              \
    { UR for (int j_ = 0; j_ < 2; ++j_) {                                                          \
        bF[(NH2) * 2 + j_][0] = *(const s16x8*)&smem[(BUF) + 16384 + bOff0 + ((NH2) * 2 + j_) * 1024]; \
        bF[(NH2) * 2 + j_][1] = *(const s16x8*)&smem[(BUF) + 16384 + bOff1 + ((NH2) * 2 + j_) * 1024]; } }

#define MFMAQ(MF0, NF0)                                                                            \
    { __builtin_amdgcn_s_setprio(1);                                                               \
      UR for (int i_ = 0; i_ < 4; ++i_)                                                            \
        UR for (int j_ = 0; j_ < 2; ++j_)                                                          \
          UR for (int k_ = 0; k_ < 2; ++k_)                                                        \
            acc[(MF0) + i_][(NF0) + j_] = __builtin_amdgcn_mfma_f32_16x16x32_bf16(                 \
                aF[i_][k_], bF[(NF0) + j_][k_], acc[(MF0) + i_][(NF0) + j_], 0, 0, 0);             \
      __builtin_amdgcn_s_setprio(0); }

#define TILE(BUFR, BUFW, DOSTAGE)                                                                  \
    {                                                                                              \
        LDA(BUFR, 0); LDB(BUFR, 0);                                                                \
        if (DOSTAGE) { GLALL(BUFW); aStage += BK; bStage += BK; }                                  \
        MFMAQ(0, 0);                                                                               \
        LDB(BUFR, 1);                                                                              \
        MFMAQ(0, 2);                                                                               \
        LDA(BUFR, 1);                                                                              \
        MFMAQ(4, 2);                                                                               \
        MFMAQ(4, 0);                                                                               \
        asm volatile("s_waitcnt vmcnt(0)" ::: "memory");                                           \
        asm volatile("s_barrier" ::: "memory");                                                    \
    }

    GLALL(0)
    aStage += BK; bStage += BK;
    asm volatile("s_waitcnt vmcnt(0)" ::: "memory");
    asm volatile("s_barrier" ::: "memory");

    for (int i = 0; i < 15; ++i) {
        TILE(0, 32768, 1);
        TILE(32768, 0, 1);
    }
    TILE(0, 32768, 1);
    TILE(32768, 0, 0);

#undef GL
#undef GLALL
#undef LDA
#undef LDB
#undef MFMAQ
#undef TILE

    // ---- epilogue: per chunk c (128 cols = head hc = 2*nt+c): rms over chunk cols, scale, store
    for (int c = 0; c < 2; ++c) {
        if (((wv >> 1) & 1) == c) {
            UR for (int mf = 0; mf < 8; ++mf)
                UR for (int nf = 0; nf < 4; ++nf)
                    UR for (int r = 0; r < 4; ++r)
                        qsc[wm * 128 + mf * 16 + (lane >> 4) * 4 + r][(wv & 1) * 64 + nf * 16 + l15] =
                            f2bf(acc[mf][nf][r]);
        }
        __syncthreads();

        {
            const int r2 = tid >> 1, ch = (tid & 1) * 64;
            const unsigned short* row = &qsc[r2][ch];
            float s2 = 0.f;
            UR for (int dw = 0; dw < 32; ++dw) {
                unsigned int v = *(const unsigned int*)&row[dw * 2];
                float f0 = bf2f((unsigned short)(v & 0xffff));
                float f1 = bf2f((unsigned short)(v >> 16));
                s2 += f0 * f0 + f1 * f1;
            }
            s2 += __shfl_xor(s2, 1);
            const float rq = rsqrtf(s2 * (1.0f / 128.0f) + 1e-6f);

            const int hc = nt * 2 + c;
            unsigned short* dst = kn_ws + (size_t)(m0 + r2) * (NH * DH) + hc * DH + ch;
            UR for (int i = 0; i < 8; ++i) {
                u32x4 v;
                float f0, f1;
                f0 = bf2f(row[i * 8 + 0]) * rq * wsm[ch + i * 8 + 0];
                f1 = bf2f(row[i * 8 + 1]) * rq * wsm[ch + i * 8 + 1];
                v.x = pack2(f0, f1);
                f0 = bf2f(row[i * 8 + 2]) * rq * wsm[ch + i * 8 + 2];
                f1 = bf2f(row[i * 8 + 3]) * rq * wsm[ch + i * 8 + 3];
                v.y = pack2(f0, f1);
                f0 = bf2f(row[i * 8 + 4]) * rq * wsm[ch + i * 8 + 4];
                f1 = bf2f(row[i * 8 + 5]) * rq * wsm[ch + i * 8 + 5];
                v.z = pack2(f0, f1);
                f0 = bf2f(row[i * 8 + 6]) * rq * wsm[ch + i * 8 + 6];
                f1 = bf2f(row[i * 8 + 7]) * rq * wsm[ch + i * 8 + 7];
                v.w = pack2(f0, f1);
                *(u32x4*)(dst + i * 8) = v;
            }
        }
        __syncthreads();
    }
}

// ---------------- Kernel B (R8-proven, frozen): 256x256-tile q-proj + RMSNorm + MFMA sink gate
__global__ __launch_bounds__(512, 2) void qscore_bf16(const unsigned short* __restrict__ hid,
                                                      const unsigned short* __restrict__ Wq,
                                                      const float* __restrict__ bq,
                                                      const float* __restrict__ qnw,
                                                      const float* __restrict__ bb,
                                                      const float* __restrict__ kbase,
                                                      const unsigned short* __restrict__ kn_ws,
                                                      float* __restrict__ out)
{
    __shared__ alignas(16) unsigned short smem[65536];
    __shared__ alignas(16) unsigned short kbn[NSINK][136];
    __shared__ float rms_l[256];
    __shared__ float l_l[256];
    __shared__ float wsm[128];
    unsigned short (*qsc)[132] = (unsigned short(*)[132])smem;

    const int tid = threadIdx.x, lane = tid & 63, wv = tid >> 6;
    const int wm = wv >> 2, wn = wv & 3;
    const int nt = blockIdx.x;
    const int m0 = blockIdx.y * 256;
    const int n0 = nt * 256;
    const int h  = nt >> 1;

    if (tid < 128) wsm[tid] = qnw[tid];
    if (tid < 256) {
        const int ts = tid >> 4, d0 = (tid & 15) * 8;
        const float* src = kbase + ((size_t)h * NSINK + ts) * DH + d0;
        float4 x = *(const float4*)src;
        float4 y = *(const float4*)(src + 4);
        const float* w = qnw + d0;
        u32x4 v;
        v.x = pack2(x.x * w[0], x.y * w[1]);
        v.y = pack2(x.z * w[2], x.w * w[3]);
        v.z = pack2(y.x * w[4], y.y * w[5]);
        v.w = pack2(y.z * w[6], y.w * w[7]);
        *(u32x4*)&kbn[ts][d0] = v;
    }

    const int srow = tid >> 3;
    const int so0 = srow * DIN + (((tid & 7) ^ (srow & 7)) * 8);

    const int l15 = lane & 15;
    const int slotA = ((lane >> 4) ^ (lane & 7)) * 8;
    const int aOff0 = (wm * 128 + l15) * 64 + slotA;
    const int aOff1 = aOff0 ^ 32;
    const int bOff0 = (wn * 64 + l15) * 64 + slotA;
    const int bOff1 = bOff0 ^ 32;

    const unsigned short* aStage = hid + (size_t)m0 * DIN;
    const unsigned short* bStage = Wq + (size_t)n0 * DIN;

    f32x4 acc[8][4];
    UR for (int m = 0; m < 8; ++m)
        UR for (int n = 0; n < 4; ++n)
            acc[m][n] = f32x4{0.f, 0.f, 0.f, 0.f};

    s16x8 aF[4][2], bF[4][2];

#define GL(LDSB, SRC)                                                                              \
    __builtin_amdgcn_global_load_lds(                                                              \
        (const __attribute__((address_space(1))) unsigned int*)((SRC) + so0),                      \
        (__attribute__((address_space(3))) unsigned int*)(smem + (LDSB) + tid * 8), 16, 0, 0);     \
    __builtin_amdgcn_global_load_lds(                                                              \
        (const __attribute__((address_space(1))) unsigned int*)((SRC) + so0 + 64 * DIN),           \
        (__attribute__((address_space(3))) unsigned int*)(smem + (LDSB) + 4096 + tid * 8), 16, 0, 0);

#define GLALL(BUFW)                                                                                \
    { GL((BUFW) + 0,     aStage)             GL((BUFW) + 8192,  aStage + 128 * DIN)                \
      GL((BUFW) + 16384, bStage)             GL((BUFW) + 24576, bStage + 128 * DIN) }

#define LDA(BUF, QH)                                                                               \
    { UR for (int i_ = 0; i_ < 4; ++i_) {                                                          \
        aF[i_][0] = *(const s16x8*)&smem[(BUF) + aOff0 + ((QH) * 4 + i_) * 1024];                  \
        aF[i_][1] = *(const s16x8*)&smem[(BUF) + aOff1 + ((QH) * 4 + i_) * 1024]; } }

#define LDB(BUF, NH2)                                                                              \
    { UR for (int j_ = 0; j_ < 2; ++j_) {                                                          \
        bF[(NH2) * 2 + j_][0] = *(const s16x8*)&smem[(BUF) + 16384 + bOff0 + ((NH2) * 2 + j_) * 1024]; \
        bF[(NH2) * 2 + j_][1] = *(const s16x8*)&smem[(BUF) + 16384 + bOff1 + ((NH2) * 2 + j_) * 1024]; } }

#define MFMAQ(MF0, NF0)                                                                            \
    { __builtin_amdgcn_s_setprio(1);                                                               \
      UR for (int i_ = 0; i_ < 4; ++i_)                                                            \
        UR for (int j_ = 0; j_ < 2; ++j_)                                                          \
          UR for (int k_ = 0; k_ < 2; ++k_)                                                        \
            acc[(MF0) + i_][(NF0) + j_] = __builtin_amdgcn_mfma_f32_16x16x32_bf16(                 \
                aF[i_][k_], bF[(NF0) + j_][k_], acc[(MF0) + i_][(NF0) + j_], 0, 0, 0);             \
      __builtin_amdgcn_s_setprio(0); }

#define TILE(BUFR, BUFW, DOSTAGE)                                                                  \
    {                                                                                              \
        LDA(BUFR, 0); LDB(BUFR, 0);                                                                \
        if (DOSTAGE) { GLALL(BUFW); aStage += BK; bStage += BK; }                                  \
        MFMAQ(0, 0);                                                                               \
        LDB(BUFR, 1);                                                                              \
        MFMAQ(0, 2);                                                                               \
        LDA(BUFR, 1);                                                                              \
        MFMAQ(4, 2);                                                                               \
        MFMAQ(4, 0);                                                                               \
        asm volatile("s_waitcnt vmcnt(0)" ::: "memory");                                           \
        asm volatile("s_barrier" ::: "memory");                                                    \
    }

    GLALL(0)
    aStage += BK; bStage += BK;
    asm volatile("s_waitcnt vmcnt(0)" ::: "memory");
    asm volatile("s_barrier" ::: "memory");

    for (int i = 0; i < 15; ++i) {
        TILE(0, 32768, 1);
        TILE(32768, 0, 1);
    }
    TILE(0, 32768, 1);
    TILE(32768, 0, 0);

#undef GL
#undef GLALL
#undef LDA
#undef LDB
#undef MFMAQ
#undef TILE

    float bqv[4];
    UR for (int nf = 0; nf < 4; ++nf)
        bqv[nf] = bq[n0 + wn * 64 + nf * 16 + l15];

    for (int c = 0; c < 2; ++c) {
        if (((wv >> 1) & 1) == c) {
            UR for (int mf = 0; mf < 8; ++mf)
                UR for (int nf = 0; nf < 4; ++nf)
                    UR for (int r = 0; r < 4; ++r)
                        qsc[wm * 128 + mf * 16 + (lane >> 4) * 4 + r][(wv & 1) * 64 + nf * 16 + l15] =
                            f2bf(acc[mf][nf][r] + bqv[nf]);
        }
        __syncthreads();

        const float bvalc = 2.0f * bb[h * NG + ((nt * 2 + c) & 3)];
        {
            const int r2 = tid >> 1, ch = (tid & 1) * 64;
            const unsigned short* qrow = &qsc[r2][ch];
            const unsigned short* kg = kn_ws + (size_t)(m0 + r2) * (NH * DH) + h * DH + ch;
            const float* wp = &wsm[ch];
            float s2 = 0.f, skq = 0.f;
            UR for (int i = 0; i < 8; ++i) {
                u32x4 kv = *(const u32x4*)(kg + i * 8);
                UR for (int j = 0; j < 4; ++j) {
                    unsigned int qv = *(const unsigned int*)&qrow[i * 8 + j * 2];
                    unsigned int kw = kv[j];
                    float q0 = bf2f((unsigned short)(qv & 0xffff));
                    float q1 = bf2f((unsigned short)(qv >> 16));
                    float k0 = bf2f((unsigned short)(kw & 0xffff));
                    float k1 = bf2f((unsigned short)(kw >> 16));
                    s2  += q0 * q0 + q1 * q1;
                    skq += q0 * k0 * wp[i * 8 + j * 2] + q1 * k1 * wp[i * 8 + j * 2 + 1];
                }
            }
            s2  += __shfl_xor(s2, 1);
            skq += __shfl_xor(skq, 1);
            if ((tid & 1) == 0) {
                const float rs = rsqrtf(s2 * (1.0f / 128.0f) + 1e-6f) * 0.08838834764831845f;
                rms_l[r2] = rs;
                l_l[r2]   = skq * rs + bvalc;
            }
        }
        __syncthreads();

        {
            f32x4 sacc0 = f32x4{0.f, 0.f, 0.f, 0.f};
            f32x4 sacc1 = f32x4{0.f, 0.f, 0.f, 0.f};
            const int ar = wv * 32 + l15;
            const int kc = (lane >> 4) * 8;
            UR for (int ks = 0; ks < 4; ++ks) {
                s16x8 bf_ = *(const s16x8*)&kbn[l15][ks * 32 + kc];
                s16x8 a0  = *(const s16x8*)&qsc[ar][ks * 32 + kc];
                s16x8 a1  = *(const s16x8*)&qsc[ar + 16][ks * 32 + kc];
                sacc0 = __builtin_amdgcn_mfma_f32_16x16x32_bf16(a0, bf_, sacc0, 0, 0, 0);
                sacc1 = __builtin_amdgcn_mfma_f32_16x16x32_bf16(a1, bf_, sacc1, 0, 0, 0);
            }
            UR for (int mt = 0; mt < 2; ++mt) {
                f32x4 sa = mt ? sacc1 : sacc0;
                UR for (int r = 0; r < 4; ++r) {
                    const int row = wv * 32 + mt * 16 + (lane >> 4) * 4 + r;
                    float e = __expf(sa[r] * rms_l[row] - l_l[row]);
                    e += __shfl_xor(e, 1);
                    e += __shfl_xor(e, 2);
                    e += __shfl_xor(e, 4);
                    e += __shfl_xor(e, 8);
                    if (l15 == 0)
                        atomicAdd(&out[(size_t)h * S_TOK + m0 + row], 0.25f / (1.0f + e));
                }
            }
        }
        __syncthreads();
    }
}

extern "C" void kernel_launch(void* const* d_in, const int* in_sizes, int n_in,
                              void* d_out, int out_size, void* d_ws, size_t ws_size,
                              hipStream_t stream)
{
    const float* hid = (const float*)d_in[0];
    const float* Wq  = (const float*)d_in[1];
    const float* bq  = (const float*)d_in[2];
    const float* Wk  = (const float*)d_in[3];
    const float* qnw = (const float*)d_in[4];
    const float* knw = (const float*)d_in[5];
    const float* bb  = (const float*)d_in[6];
    const float* kb  = (const float*)d_in[7];
    float* out = (float*)d_out;

    (void)hipMemsetAsync(d_out, 0, (size_t)out_size * sizeof(float), stream);

    const size_t HID_E = (size_t)S_TOK * DIN;
    const size_t WQ_E  = (size_t)NH * NG * DH * DIN;
    const size_t WK_E  = (size_t)NH * DH * DIN;

    unsigned short* hid_b = (unsigned short*)d_ws;
    unsigned short* wq_b  = hid_b + HID_E;
    unsigned short* wk_b  = wq_b + WQ_E;
    unsigned short* kn_ws = wk_b + WK_E;

    cvt_all_kernel<<<2816, 256, 0, stream>>>(hid, Wq, Wk, hid_b, wq_b, wk_b);

    kproj256_bf16<<<dim3(4, S_TOK / 256), dim3(512), 0, stream>>>(hid_b, wk_b, knw, kn_ws);
    qscore_bf16<<<dim3(NH * NG / 2, S_TOK / 256), dim3(512), 0, stream>>>(hid_b, wq_b, bq, qnw, bb, kb, kn_ws, out);
}